// Round 1
// baseline (36.800 us; speedup 1.0000x reference)
//
#include <hip/hip_runtime.h>

// YOLOv1 loss: pred (N,7,7,30) fp32, target (N,7,7,25) fp32 -> scalar fp32.
// Memory-bound streaming reduction. Two-pass deterministic reduce.

#define SS 7
#define NCLS 20
#define NBOX 2
#define PRED_C (NCLS + 5 * NBOX)   // 30
#define TGT_C  (NCLS + 5)          // 25

__device__ __forceinline__ float block_reduce(float acc) {
    // wave64 shuffle reduce
    #pragma unroll
    for (int off = 32; off; off >>= 1) acc += __shfl_down(acc, off, 64);
    __shared__ float smem[4];
    int lane = threadIdx.x & 63, wid = threadIdx.x >> 6;
    if (lane == 0) smem[wid] = acc;
    __syncthreads();
    float s = 0.f;
    if (threadIdx.x == 0) {
        #pragma unroll
        for (int w = 0; w < 4; ++w) s += smem[w];
    }
    return s;
}

__global__ void __launch_bounds__(256)
yolo_loss_partial(const float* __restrict__ pred,
                  const float* __restrict__ target,
                  float* __restrict__ partial,
                  int ncells, float inv_n) {
    const float LC = 5.0f;       // LAMBDA_COORD
    const float LN = 0.5f;       // LAMBDA_NOOBJ
    const float EPS = 1e-6f;
    const float SQE = 1e-12f;

    float acc = 0.f;
    for (int cell = blockIdx.x * blockDim.x + threadIdx.x; cell < ncells;
         cell += gridDim.x * blockDim.x) {
        const float* p = pred + (size_t)cell * PRED_C;
        const float* t = target + (size_t)cell * TGT_C;

        // pred cell: 30 floats, byte offset cell*120 -> 8-byte aligned, use float2
        float pv[PRED_C];
        const float2* p2 = reinterpret_cast<const float2*>(p);
        #pragma unroll
        for (int i = 0; i < PRED_C / 2; ++i) {
            float2 v = p2[i];
            pv[2 * i] = v.x;
            pv[2 * i + 1] = v.y;
        }
        // target cell: 25 floats, only 4-byte aligned -> scalar
        float tv[TGT_C];
        #pragma unroll
        for (int i = 0; i < TGT_C; ++i) tv[i] = t[i];

        float obj = tv[NCLS];  // 0 or 1

        // class loss (masked by obj)
        float cls = 0.f;
        #pragma unroll
        for (int c = 0; c < NCLS; ++c) {
            float d = pv[c] - tv[c];
            cls += d * d;
        }

        // target box
        float tx = tv[NCLS + 1], ty = tv[NCLS + 2];
        float tw = tv[NCLS + 3], th = tv[NCLS + 4];
        float bx1 = tx - tw * 0.5f, bx2 = tx + tw * 0.5f;
        float by1 = ty - th * 0.5f, by2 = ty + th * 0.5f;
        float tarea = tw * th;

        // box 0
        float c0 = pv[NCLS + 0];
        float x0 = pv[NCLS + 1], y0 = pv[NCLS + 2];
        float w0 = pv[NCLS + 3], h0 = pv[NCLS + 4];
        float a0x1 = x0 - w0 * 0.5f, a0x2 = x0 + w0 * 0.5f;
        float a0y1 = y0 - h0 * 0.5f, a0y2 = y0 + h0 * 0.5f;
        float iw0 = fmaxf(fminf(a0x2, bx2) - fmaxf(a0x1, bx1), 0.f);
        float ih0 = fmaxf(fminf(a0y2, by2) - fmaxf(a0y1, by1), 0.f);
        float in0 = iw0 * ih0;
        float iou0 = in0 / (w0 * h0 + tarea - in0 + EPS);

        // box 1
        float c1 = pv[NCLS + 5];
        float x1 = pv[NCLS + 6], y1 = pv[NCLS + 7];
        float w1 = pv[NCLS + 8], h1 = pv[NCLS + 9];
        float a1x1 = x1 - w1 * 0.5f, a1x2 = x1 + w1 * 0.5f;
        float a1y1 = y1 - h1 * 0.5f, a1y2 = y1 + h1 * 0.5f;
        float iw1 = fmaxf(fminf(a1x2, bx2) - fmaxf(a1x1, bx1), 0.f);
        float ih1 = fmaxf(fminf(a1y2, by2) - fmaxf(a1y1, by1), 0.f);
        float in1 = iw1 * ih1;
        float iou1 = in1 / (w1 * h1 + tarea - in1 + EPS);

        // argmax (first index wins ties, matching jnp.argmax)
        bool b0 = (iou0 >= iou1);
        float best_iou = fmaxf(iou0, iou1);
        float bx = b0 ? x0 : x1;
        float by = b0 ? y0 : y1;
        float bw = b0 ? w0 : w1;
        float bh = b0 ? h0 : h1;
        float bc = b0 ? c0 : c1;

        // coord loss (best box only, masked by obj)
        float dx = bx - tx, dy = by - ty;
        float dw = sqrtf(fmaxf(bw, SQE)) - sqrtf(fmaxf(tw, SQE));
        float dh = sqrtf(fmaxf(bh, SQE)) - sqrtf(fmaxf(th, SQE));
        float coord = LC * (dx * dx + dy * dy + dw * dw + dh * dh);

        // conf losses
        float dconf = bc - best_iou;
        float objconf = dconf * dconf;
        float noobj = LN * (c0 * c0 + c1 * c1);

        acc += obj * (cls + coord + objconf) + (1.f - obj) * noobj;
    }

    float s = block_reduce(acc);
    if (threadIdx.x == 0) partial[blockIdx.x] = s * inv_n;
}

__global__ void __launch_bounds__(256)
yolo_reduce(const float* __restrict__ partial, float* __restrict__ out, int n) {
    float acc = 0.f;
    for (int i = threadIdx.x; i < n; i += blockDim.x) acc += partial[i];
    float s = block_reduce(acc);
    if (threadIdx.x == 0) out[0] = s;
}

extern "C" void kernel_launch(void* const* d_in, const int* in_sizes, int n_in,
                              void* d_out, int out_size, void* d_ws, size_t ws_size,
                              hipStream_t stream) {
    const float* pred = (const float*)d_in[0];
    const float* target = (const float*)d_in[1];
    float* out = (float*)d_out;
    float* partial = (float*)d_ws;

    int N = in_sizes[0] / (SS * SS * PRED_C);
    int ncells = N * SS * SS;

    int nblk = 2048;
    size_t need = (size_t)nblk * sizeof(float);
    if (need > ws_size) nblk = (int)(ws_size / sizeof(float));
    if (nblk < 1) nblk = 1;

    yolo_loss_partial<<<nblk, 256, 0, stream>>>(pred, target, partial, ncells,
                                                1.0f / (float)N);
    yolo_reduce<<<1, 256, 0, stream>>>(partial, out, nblk);
}